// Round 1
// baseline (310.312 us; speedup 1.0000x reference)
//
#include <hip/hip_runtime.h>

typedef _Float16 f16;
typedef __attribute__((ext_vector_type(4))) _Float16 f16x4;
typedef __attribute__((ext_vector_type(8))) _Float16 f16x8;
typedef __attribute__((ext_vector_type(4))) float f32x4;

#define NB 2
#define NS 2048
#define NHID 2048
#define N_H 16
#define N_KV 4
#define N_HD 128

__device__ __forceinline__ void gload16(void* lds, const void* g) {
  __builtin_amdgcn_global_load_lds(
      (const __attribute__((address_space(1))) unsigned int*)g,
      (__attribute__((address_space(3))) unsigned int*)lds, 16, 0, 0);
}

// ---------------- f32 -> f16 convert (vectorized) ----------------
__global__ __launch_bounds__(256) void cvt_kernel(const float* __restrict__ in,
                                                  f16* __restrict__ out, int n4) {
  int i = blockIdx.x * 256 + threadIdx.x;
  if (i >= n4) return;
  const float4 v = reinterpret_cast<const float4*>(in)[i];
  f16x4 o = {(f16)v.x, (f16)v.y, (f16)v.z, (f16)v.w};
  reinterpret_cast<f16x4*>(out)[i] = o;
}

// ---------------- GEMM: C[M,N] = A[M,K] * B[N,K]^T ----------------
// 128x128 tile, BK=32, 4 waves (2x2 of 64x64), mfma_f32_16x16x32_f16.
// MODE 0: scatter into Q/K/V fp16 buffers ([B,H,S,D]).  MODE 1: f32 out + bias.
template <int MODE>
__global__ __launch_bounds__(256) void gemm_bt(
    const f16* __restrict__ A, const f16* __restrict__ Bm, int K,
    f16* __restrict__ q_out, f16* __restrict__ k_out, f16* __restrict__ v_out,
    float* __restrict__ f_out, const float* __restrict__ bias) {
  __shared__ f16 Alds[128 * 32];
  __shared__ f16 Blds[128 * 32];
  const int t = threadIdx.x;
  const int l = t & 63;
  const int w = t >> 6;
  const int g = l >> 4;
  const int l15 = l & 15;
  const int mb = blockIdx.y, nb = blockIdx.x;
  const int wr = w >> 1, wc = w & 1;

  f32x4 acc[4][4] = {};
  const int nK = K >> 5;
  for (int kb = 0; kb < nK; ++kb) {
    __syncthreads();
    // stage A,B tiles: each 128 rows x 32 f16 = 8KB = 512 x 16B chunks
#pragma unroll
    for (int it = 0; it < 2; ++it) {
      int cb = w * 128 + it * 64;
      int c = cb + l;
      int row = c >> 2, ci = c & 3;  // 4 chunks per 64B row
      gload16(Alds + cb * 8, A + (size_t)(mb * 128 + row) * K + kb * 32 + ci * 8);
      gload16(Blds + cb * 8, Bm + (size_t)(nb * 128 + row) * K + kb * 32 + ci * 8);
    }
    asm volatile("s_waitcnt vmcnt(0)" ::: "memory");
    __syncthreads();

    f16x8 af[4], bf[4];
#pragma unroll
    for (int mi = 0; mi < 4; ++mi)
      af[mi] = *reinterpret_cast<const f16x8*>(Alds + (wr * 64 + mi * 16 + l15) * 32 + g * 8);
#pragma unroll
    for (int ni = 0; ni < 4; ++ni)
      bf[ni] = *reinterpret_cast<const f16x8*>(Blds + (wc * 64 + ni * 16 + l15) * 32 + g * 8);
#pragma unroll
    for (int mi = 0; mi < 4; ++mi)
#pragma unroll
      for (int ni = 0; ni < 4; ++ni)
        acc[mi][ni] = __builtin_amdgcn_mfma_f32_16x16x32_f16(af[mi], bf[ni], acc[mi][ni], 0, 0, 0);
  }

  // epilogue: D[row = 4*g + r][col = l15] per 16x16 fragment
#pragma unroll
  for (int mi = 0; mi < 4; ++mi) {
    int m0 = mb * 128 + wr * 64 + mi * 16 + 4 * g;
#pragma unroll
    for (int ni = 0; ni < 4; ++ni) {
      int n = nb * 128 + wc * 64 + ni * 16 + l15;
#pragma unroll
      for (int r = 0; r < 4; ++r) {
        int mm = m0 + r;
        float val = acc[mi][ni][r];
        if (MODE == 0) {
          int b = mm >> 11, s = mm & (NS - 1);
          if (n < 2048) {
            int h = n >> 7, d = n & 127;
            q_out[(((size_t)(b * N_H + h)) * NS + s) * N_HD + d] = (f16)val;
          } else if (n < 2560) {
            int n2 = n - 2048, kvh = n2 >> 7, d = n2 & 127;
            k_out[(((size_t)(b * N_KV + kvh)) * NS + s) * N_HD + d] = (f16)val;
          } else {
            int n3 = n - 2560, kvh = n3 >> 7, d = n3 & 127;
            v_out[(((size_t)(b * N_KV + kvh)) * NS + s) * N_HD + d] = (f16)val;
          }
        } else {
          f_out[(size_t)mm * NHID + n] = val + bias[n];
        }
      }
    }
  }
}

// ---------------- V transpose: [B*NKV][S][HD] -> [B*NKV][HD][S] ----------------
__global__ __launch_bounds__(256) void transpose_v(const f16* __restrict__ V,
                                                   f16* __restrict__ Vt) {
  __shared__ f16 tt[64][72];
  int s0 = blockIdx.x * 64, d0 = blockIdx.y * 64, bk = blockIdx.z;
  const f16* Vp = V + (size_t)bk * NS * N_HD;
  f16* Vtp = Vt + (size_t)bk * N_HD * NS;
  int tid = threadIdx.x;
#pragma unroll
  for (int it = 0; it < 2; ++it) {
    int c = it * 256 + tid;
    int sr = c >> 3, dc = (c & 7) * 8;
    f16x8 v = *reinterpret_cast<const f16x8*>(Vp + (size_t)(s0 + sr) * N_HD + d0 + dc);
#pragma unroll
    for (int j = 0; j < 8; ++j) tt[dc + j][sr] = v[j];
  }
  __syncthreads();
#pragma unroll
  for (int it = 0; it < 2; ++it) {
    int c = it * 256 + tid;
    int dr = c >> 3, sc = (c & 7) * 8;
    f16x8 o;
#pragma unroll
    for (int j = 0; j < 8; ++j) o[j] = tt[dr][sc + j];
    *reinterpret_cast<f16x8*>(Vtp + (size_t)(d0 + dr) * NS + s0 + sc) = o;
  }
}

// ---------------- causal GQA flash attention ----------------
// grid: (S/64, B*NH). block 256 = 4 waves, 16 q-rows each. KBLK=64. No 1/sqrt(d).
__global__ __launch_bounds__(256) void attn_kernel(
    const f16* __restrict__ Q, const f16* __restrict__ K,
    const f16* __restrict__ Vt, f16* __restrict__ O) {
  __shared__ f16 Klds[64 * 128];   // [k][d], chunk-swizzled by (k&7)
  __shared__ f16 Vlds[128 * 64];   // [d][k], chunk-swizzled by (d&7)
  __shared__ f16 Plds[4][16 * 64]; // per-wave P, chunk-swizzled by (q&7)
  const int t = threadIdx.x, l = t & 63, w = t >> 6;
  const int g = l >> 4, l15 = l & 15;
  const int qt = blockIdx.x;
  const int bh = blockIdx.y;
  const int b = bh >> 4, h = bh & 15;
  const int kvh = h >> 2;
  const f16* Qp = Q + ((size_t)(b * N_H + h)) * NS * N_HD;
  const f16* Kp = K + ((size_t)(b * N_KV + kvh)) * NS * N_HD;
  const f16* Vp = Vt + ((size_t)(b * N_KV + kvh)) * N_HD * NS;

  // Q fragments in registers: A-op rows = l15
  const int qrow_in = qt * 64 + w * 16 + l15;
  f16x8 qf[4];
#pragma unroll
  for (int ks = 0; ks < 4; ++ks)
    qf[ks] = *reinterpret_cast<const f16x8*>(Qp + (size_t)qrow_in * N_HD + ks * 32 + g * 8);

  f32x4 oacc[8] = {};
  float mrow[4], lrow[4];
#pragma unroll
  for (int r = 0; r < 4; ++r) { mrow[r] = -3.0e38f; lrow[r] = 0.f; }
  const int q0 = qt * 64 + w * 16 + 4 * g;  // acc rows = q0 + r

  for (int kt = 0; kt <= qt; ++kt) {
    __syncthreads();
    // stage K tile [64][128]: 1024 chunks, swizzled source columns
#pragma unroll
    for (int it = 0; it < 4; ++it) {
      int cb = (it * 4 + w) * 64;
      int c = cb + l;
      int krow = c >> 4, pch = c & 15;
      int sch = (pch & 8) | ((pch ^ krow) & 7);
      gload16(Klds + cb * 8, Kp + (size_t)(kt * 64 + krow) * N_HD + sch * 8);
    }
    // stage V^T tile [128][64]
#pragma unroll
    for (int it = 0; it < 4; ++it) {
      int cb = (it * 4 + w) * 64;
      int c = cb + l;
      int drow = c >> 3, pch = c & 7;
      int sch = (pch ^ drow) & 7;
      gload16(Vlds + cb * 8, Vp + (size_t)drow * NS + kt * 64 + sch * 8);
    }
    asm volatile("s_waitcnt vmcnt(0)" ::: "memory");
    __syncthreads();

    // S = Q K^T : acc D[q=4g+r][kpos=l15+16nt]
    f32x4 sacc[4];
#pragma unroll
    for (int nt = 0; nt < 4; ++nt) {
      f32x4 z = {0.f, 0.f, 0.f, 0.f};
#pragma unroll
      for (int ks = 0; ks < 4; ++ks) {
        int kr = nt * 16 + l15;
        int ch = ks * 4 + g;
        int sw = (ch & 8) | ((ch ^ kr) & 7);
        f16x8 kf = *reinterpret_cast<const f16x8*>(Klds + kr * 128 + sw * 8);
        z = __builtin_amdgcn_mfma_f32_16x16x32_f16(qf[ks], kf, z, 0, 0, 0);
      }
      sacc[nt] = z;
    }

    // causal mask + wave-parallel online softmax
    float p[4][4], alpha[4];
#pragma unroll
    for (int r = 0; r < 4; ++r) {
      int qg = q0 + r;
      float mx = -3.0e38f;
#pragma unroll
      for (int nt = 0; nt < 4; ++nt) {
        int kg = kt * 64 + nt * 16 + l15;
        float sv = (kg <= qg) ? sacc[nt][r] : -3.0e38f;
        p[nt][r] = sv;
        mx = fmaxf(mx, sv);
      }
#pragma unroll
      for (int off = 8; off >= 1; off >>= 1) mx = fmaxf(mx, __shfl_xor(mx, off));
      float mn = fmaxf(mrow[r], mx);
      alpha[r] = __expf(mrow[r] - mn);
      mrow[r] = mn;
      float rs = 0.f;
#pragma unroll
      for (int nt = 0; nt < 4; ++nt) {
        float pv = __expf(p[nt][r] - mn);
        p[nt][r] = pv;
        rs += pv;
      }
#pragma unroll
      for (int off = 8; off >= 1; off >>= 1) rs += __shfl_xor(rs, off);
      lrow[r] = lrow[r] * alpha[r] + rs;
    }
#pragma unroll
    for (int dt = 0; dt < 8; ++dt)
#pragma unroll
      for (int r = 0; r < 4; ++r) oacc[dt][r] *= alpha[r];

    // P -> per-wave LDS (swizzled), then read back as A-op fragments
#pragma unroll
    for (int nt = 0; nt < 4; ++nt)
#pragma unroll
      for (int r = 0; r < 4; ++r) {
        int ql = 4 * g + r;
        int kp = nt * 16 + l15;
        int ch = kp >> 3;
        int idx = ql * 64 + (ch ^ (ql & 7)) * 8 + (kp & 7);
        Plds[w][idx] = (f16)p[nt][r];
      }
    asm volatile("s_waitcnt lgkmcnt(0)" ::: "memory");
    __builtin_amdgcn_sched_barrier(0);

    f16x8 pa[2];
#pragma unroll
    for (int ks2 = 0; ks2 < 2; ++ks2) {
      int ch = ks2 * 4 + g;
      pa[ks2] = *reinterpret_cast<const f16x8*>(&Plds[w][l15 * 64 + (ch ^ (l15 & 7)) * 8]);
    }
    // O += P V : B-op = V[k][d] from Vlds[d][k]
#pragma unroll
    for (int dt = 0; dt < 8; ++dt)
#pragma unroll
      for (int ks2 = 0; ks2 < 2; ++ks2) {
        int d = dt * 16 + l15;
        int ch = ks2 * 4 + g;
        f16x8 vf = *reinterpret_cast<const f16x8*>(Vlds + d * 64 + (ch ^ (d & 7)) * 8);
        oacc[dt] = __builtin_amdgcn_mfma_f32_16x16x32_f16(pa[ks2], vf, oacc[dt], 0, 0, 0);
      }
  }

  // normalize + write attn_out [B*S][NH*HD] fp16
#pragma unroll
  for (int r = 0; r < 4; ++r) {
    float inv = 1.0f / lrow[r];
    int qg = q0 + r;
    f16* orow = O + (size_t)(b * NS + qg) * NHID + h * N_HD;
#pragma unroll
    for (int dt = 0; dt < 8; ++dt) orow[dt * 16 + l15] = (f16)(oacc[dt][r] * inv);
  }
}

extern "C" void kernel_launch(void* const* d_in, const int* in_sizes, int n_in,
                              void* d_out, int out_size, void* d_ws, size_t ws_size,
                              hipStream_t stream) {
  const float* hs = (const float*)d_in[0];
  const float* Wq = (const float*)d_in[1];
  const float* Wk = (const float*)d_in[2];
  const float* Wv = (const float*)d_in[3];
  const float* Wo = (const float*)d_in[4];
  const float* bo = (const float*)d_in[5];
  float* out = (float*)d_out;

  char* ws = (char*)d_ws;
  // layout (bytes): X 16MB | Wqkv 12MB | Wo 8MB | Q 16MB | K 4MB | V 4MB | Vt 4MB  = 64MiB
  f16* Xh   = (f16*)(ws);
  f16* Wqkv = (f16*)(ws + 16777216);
  f16* Woh  = (f16*)(ws + 29360128);
  f16* Qb   = (f16*)(ws + 37748736);
  f16* Kb   = (f16*)(ws + 54525952);
  f16* Vb   = (f16*)(ws + 58720256);
  f16* Vtb  = (f16*)(ws + 62914560);
  f16* Ob   = Xh;  // X dead after QKV GEMM; reuse for attention output

  cvt_kernel<<<8192, 256, 0, stream>>>(hs, Xh, 2097152);
  cvt_kernel<<<4096, 256, 0, stream>>>(Wq, Wqkv, 1048576);
  cvt_kernel<<<1024, 256, 0, stream>>>(Wk, Wqkv + (size_t)2048 * 2048, 262144);
  cvt_kernel<<<1024, 256, 0, stream>>>(Wv, Wqkv + (size_t)2560 * 2048, 262144);
  cvt_kernel<<<4096, 256, 0, stream>>>(Wo, Woh, 1048576);

  gemm_bt<0><<<dim3(24, 32), 256, 0, stream>>>(Xh, Wqkv, 2048, Qb, Kb, Vb, nullptr, nullptr);
  transpose_v<<<dim3(32, 2, 8), 256, 0, stream>>>(Vb, Vtb);
  attn_kernel<<<dim3(32, 32), 256, 0, stream>>>(Qb, Kb, Vtb, Ob);
  gemm_bt<1><<<dim3(16, 32), 256, 0, stream>>>(Ob, Woh, 2048, nullptr, nullptr, nullptr, out, bo);
}

// Round 2
// 237.999 us; speedup vs baseline: 1.3038x; 1.3038x over previous
//
#include <hip/hip_runtime.h>

typedef _Float16 f16;
typedef __attribute__((ext_vector_type(4))) _Float16 f16x4;
typedef __attribute__((ext_vector_type(8))) _Float16 f16x8;
typedef __attribute__((ext_vector_type(4))) float f32x4;

#define NB 2
#define NS 2048
#define NHID 2048
#define N_H 16
#define N_KV 4
#define N_HD 128

__device__ __forceinline__ void gload16(void* lds, const void* g) {
  __builtin_amdgcn_global_load_lds(
      (const __attribute__((address_space(1))) unsigned int*)g,
      (__attribute__((address_space(3))) unsigned int*)lds, 16, 0, 0);
}

// ---------------- f32 -> f16 convert (vectorized) ----------------
__global__ __launch_bounds__(256) void cvt_kernel(const float* __restrict__ in,
                                                  f16* __restrict__ out, int n4) {
  int i = blockIdx.x * 256 + threadIdx.x;
  if (i >= n4) return;
  const float4 v = reinterpret_cast<const float4*>(in)[i];
  f16x4 o = {(f16)v.x, (f16)v.y, (f16)v.z, (f16)v.w};
  reinterpret_cast<f16x4*>(out)[i] = o;
}

// 3-source convert into one contiguous dest (Wq|Wk|Wv)
__global__ __launch_bounds__(256) void cvt3_kernel(const float* __restrict__ a, int na4,
                                                   const float* __restrict__ b, int nb4,
                                                   const float* __restrict__ c, int nc4,
                                                   f16* __restrict__ out) {
  int i = blockIdx.x * 256 + threadIdx.x;
  if (i >= na4 + nb4 + nc4) return;
  const float* src;
  int j;
  if (i < na4) { src = a; j = i; }
  else if (i < na4 + nb4) { src = b; j = i - na4; }
  else { src = c; j = i - na4 - nb4; }
  const float4 v = reinterpret_cast<const float4*>(src)[j];
  f16x4 o = {(f16)v.x, (f16)v.y, (f16)v.z, (f16)v.w};
  reinterpret_cast<f16x4*>(out)[i] = o;
}

// ---------------- GEMM: C[M,N] = A[M,K] * B[N,K]^T ----------------
// 128x128 tile, BK=32, 4 waves (2x2 of 64x64), mfma_f32_16x16x32_f16.
// MODE 0: scatter into Q/K/V fp16 buffers ([B,H,S,D]).  MODE 1: f32 out + bias.
template <int MODE>
__global__ __launch_bounds__(256) void gemm_bt(
    const f16* __restrict__ A, const f16* __restrict__ Bm, int K,
    f16* __restrict__ q_out, f16* __restrict__ k_out, f16* __restrict__ v_out,
    float* __restrict__ f_out, const float* __restrict__ bias) {
  __shared__ f16 Alds[128 * 32];
  __shared__ f16 Blds[128 * 32];
  const int t = threadIdx.x;
  const int l = t & 63;
  const int w = t >> 6;
  const int g = l >> 4;
  const int l15 = l & 15;
  const int mb = blockIdx.y, nb = blockIdx.x;
  const int wr = w >> 1, wc = w & 1;

  f32x4 acc[4][4] = {};
  const int nK = K >> 5;
  for (int kb = 0; kb < nK; ++kb) {
    __syncthreads();
    // stage A,B tiles: each 128 rows x 32 f16 = 8KB = 512 x 16B chunks
#pragma unroll
    for (int it = 0; it < 2; ++it) {
      int cb = w * 128 + it * 64;
      int c = cb + l;
      int row = c >> 2, ci = c & 3;  // 4 chunks per 64B row
      gload16(Alds + cb * 8, A + (size_t)(mb * 128 + row) * K + kb * 32 + ci * 8);
      gload16(Blds + cb * 8, Bm + (size_t)(nb * 128 + row) * K + kb * 32 + ci * 8);
    }
    asm volatile("s_waitcnt vmcnt(0)" ::: "memory");
    __syncthreads();

    f16x8 af[4], bf[4];
#pragma unroll
    for (int mi = 0; mi < 4; ++mi)
      af[mi] = *reinterpret_cast<const f16x8*>(Alds + (wr * 64 + mi * 16 + l15) * 32 + g * 8);
#pragma unroll
    for (int ni = 0; ni < 4; ++ni)
      bf[ni] = *reinterpret_cast<const f16x8*>(Blds + (wc * 64 + ni * 16 + l15) * 32 + g * 8);
#pragma unroll
    for (int mi = 0; mi < 4; ++mi)
#pragma unroll
      for (int ni = 0; ni < 4; ++ni)
        acc[mi][ni] = __builtin_amdgcn_mfma_f32_16x16x32_f16(af[mi], bf[ni], acc[mi][ni], 0, 0, 0);
  }

  // epilogue: D[row = 4*g + r][col = l15] per 16x16 fragment
#pragma unroll
  for (int mi = 0; mi < 4; ++mi) {
    int m0 = mb * 128 + wr * 64 + mi * 16 + 4 * g;
#pragma unroll
    for (int ni = 0; ni < 4; ++ni) {
      int n = nb * 128 + wc * 64 + ni * 16 + l15;
#pragma unroll
      for (int r = 0; r < 4; ++r) {
        int mm = m0 + r;
        float val = acc[mi][ni][r];
        if (MODE == 0) {
          int b = mm >> 11, s = mm & (NS - 1);
          if (n < 2048) {
            int h = n >> 7, d = n & 127;
            q_out[(((size_t)(b * N_H + h)) * NS + s) * N_HD + d] = (f16)val;
          } else if (n < 2560) {
            int n2 = n - 2048, kvh = n2 >> 7, d = n2 & 127;
            k_out[(((size_t)(b * N_KV + kvh)) * NS + s) * N_HD + d] = (f16)val;
          } else {
            int n3 = n - 2560, kvh = n3 >> 7, d = n3 & 127;
            v_out[(((size_t)(b * N_KV + kvh)) * NS + s) * N_HD + d] = (f16)val;
          }
        } else {
          f_out[(size_t)mm * NHID + n] = val + bias[n];
        }
      }
    }
  }
}

// ---------------- V transpose: [B*NKV][S][HD] -> [B*NKV][HD][S] ----------------
__global__ __launch_bounds__(256) void transpose_v(const f16* __restrict__ V,
                                                   f16* __restrict__ Vt) {
  __shared__ f16 tt[64][72];
  int s0 = blockIdx.x * 64, d0 = blockIdx.y * 64, bk = blockIdx.z;
  const f16* Vp = V + (size_t)bk * NS * N_HD;
  f16* Vtp = Vt + (size_t)bk * N_HD * NS;
  int tid = threadIdx.x;
#pragma unroll
  for (int it = 0; it < 2; ++it) {
    int c = it * 256 + tid;
    int sr = c >> 3, dc = (c & 7) * 8;
    f16x8 v = *reinterpret_cast<const f16x8*>(Vp + (size_t)(s0 + sr) * N_HD + d0 + dc);
#pragma unroll
    for (int j = 0; j < 8; ++j) tt[dc + j][sr] = v[j];
  }
  __syncthreads();
#pragma unroll
  for (int it = 0; it < 2; ++it) {
    int c = it * 256 + tid;
    int dr = c >> 3, sc = (c & 7) * 8;
    f16x8 o;
#pragma unroll
    for (int j = 0; j < 8; ++j) o[j] = tt[dr][sc + j];
    *reinterpret_cast<f16x8*>(Vtp + (size_t)(d0 + dr) * NS + s0 + sc) = o;
  }
}

// ---------------- causal GQA flash attention ----------------
// Paired q-tiles per block: block pi handles q-tiles {pi, 31-pi} sharing one
// K/V staging; uniform 33 compute-units per block. Double-buffered staging,
// stage(kt+1) issued before compute(kt)  (T3-minimum pipeline).
__device__ __forceinline__ void stage_kv(const f16* __restrict__ Kp,
                                         const f16* __restrict__ Vp,
                                         f16* Kl, f16* Vl, int kt, int w, int l) {
#pragma unroll
  for (int it = 0; it < 4; ++it) {
    int cb = (it * 4 + w) * 64;
    int c = cb + l;
    int krow = c >> 4, pch = c & 15;
    int sch = (pch & 8) | ((pch ^ krow) & 7);
    gload16(Kl + cb * 8, Kp + (size_t)(kt * 64 + krow) * N_HD + sch * 8);
  }
#pragma unroll
  for (int it = 0; it < 4; ++it) {
    int cb = (it * 4 + w) * 64;
    int c = cb + l;
    int drow = c >> 3, pch = c & 7;
    int sch = (pch ^ drow) & 7;
    gload16(Vl + cb * 8, Vp + (size_t)drow * NS + kt * 64 + sch * 8);
  }
}

__device__ __forceinline__ void attn_step(
    const f16x8* qf, f32x4* oacc, float* mrow, float* lrow, int q0, int kt,
    const f16* Kl, const f16* Vl, f16* Pw, int g, int l15, bool diag) {
  // S = Q K^T : acc D[q=4g+r][kpos=l15+16nt]
  f32x4 sacc[4];
#pragma unroll
  for (int nt = 0; nt < 4; ++nt) {
    f32x4 z = {0.f, 0.f, 0.f, 0.f};
#pragma unroll
    for (int ks = 0; ks < 4; ++ks) {
      int kr = nt * 16 + l15;
      int ch = ks * 4 + g;
      int sw = (ch & 8) | ((ch ^ kr) & 7);
      f16x8 kf = *reinterpret_cast<const f16x8*>(Kl + kr * 128 + sw * 8);
      z = __builtin_amdgcn_mfma_f32_16x16x32_f16(qf[ks], kf, z, 0, 0, 0);
    }
    sacc[nt] = z;
  }

  // causal mask (diagonal tile only) + wave-parallel online softmax
  float p[4][4], alpha[4];
#pragma unroll
  for (int r = 0; r < 4; ++r) {
    int qg = q0 + r;
    float mx = -3.0e38f;
#pragma unroll
    for (int nt = 0; nt < 4; ++nt) {
      float sv = sacc[nt][r];
      if (diag) {
        int kg = kt * 64 + nt * 16 + l15;
        if (kg > qg) sv = -3.0e38f;
      }
      p[nt][r] = sv;
      mx = fmaxf(mx, sv);
    }
#pragma unroll
    for (int off = 8; off >= 1; off >>= 1) mx = fmaxf(mx, __shfl_xor(mx, off));
    float mn = fmaxf(mrow[r], mx);
    alpha[r] = __expf(mrow[r] - mn);
    mrow[r] = mn;
    float rs = 0.f;
#pragma unroll
    for (int nt = 0; nt < 4; ++nt) {
      float pv = __expf(p[nt][r] - mn);
      p[nt][r] = pv;
      rs += pv;
    }
#pragma unroll
    for (int off = 8; off >= 1; off >>= 1) rs += __shfl_xor(rs, off);
    lrow[r] = lrow[r] * alpha[r] + rs;
  }
#pragma unroll
  for (int dt = 0; dt < 8; ++dt)
#pragma unroll
    for (int r = 0; r < 4; ++r) oacc[dt][r] *= alpha[r];

  // P -> per-wave LDS (swizzled), then read back as A-op fragments
#pragma unroll
  for (int nt = 0; nt < 4; ++nt)
#pragma unroll
    for (int r = 0; r < 4; ++r) {
      int ql = 4 * g + r;
      int kp = nt * 16 + l15;
      int ch = kp >> 3;
      int idx = ql * 64 + (ch ^ (ql & 7)) * 8 + (kp & 7);
      Pw[idx] = (f16)p[nt][r];
    }
  asm volatile("s_waitcnt lgkmcnt(0)" ::: "memory");
  __builtin_amdgcn_sched_barrier(0);

  f16x8 pa[2];
#pragma unroll
  for (int ks2 = 0; ks2 < 2; ++ks2) {
    int ch = ks2 * 4 + g;
    pa[ks2] = *reinterpret_cast<const f16x8*>(&Pw[l15 * 64 + (ch ^ (l15 & 7)) * 8]);
  }
  // O += P V : B-op = V[k][d] from Vl[d][k]
#pragma unroll
  for (int dt = 0; dt < 8; ++dt)
#pragma unroll
    for (int ks2 = 0; ks2 < 2; ++ks2) {
      int d = dt * 16 + l15;
      int ch = ks2 * 4 + g;
      f16x8 vf = *reinterpret_cast<const f16x8*>(Vl + d * 64 + (ch ^ (d & 7)) * 8);
      oacc[dt] = __builtin_amdgcn_mfma_f32_16x16x32_f16(pa[ks2], vf, oacc[dt], 0, 0, 0);
    }
}

__global__ __launch_bounds__(256, 2) void attn_kernel(
    const f16* __restrict__ Q, const f16* __restrict__ K,
    const f16* __restrict__ Vt, f16* __restrict__ O) {
  __shared__ f16 Klds[2][64 * 128];   // [k][d], chunk-swizzled by (k&7)
  __shared__ f16 Vlds[2][128 * 64];   // [d][k], chunk-swizzled by (d&7)
  __shared__ f16 Plds[4][16 * 64];    // per-wave P, chunk-swizzled by (q&7)
  const int t = threadIdx.x, l = t & 63, w = t >> 6;
  const int g = l >> 4, l15 = l & 15;
  const int pi = blockIdx.x;          // 0..15
  const int qtA = pi, qtB = 31 - pi;
  const int bh = blockIdx.y;
  const int b = bh >> 4, h = bh & 15;
  const int kvh = h >> 2;
  const f16* Qp = Q + ((size_t)(b * N_H + h)) * NS * N_HD;
  const f16* Kp = K + ((size_t)(b * N_KV + kvh)) * NS * N_HD;
  const f16* Vp = Vt + ((size_t)(b * N_KV + kvh)) * N_HD * NS;

  // Q fragments in registers for both tiles: A-op rows = l15
  f16x8 qfA[4], qfB[4];
  const int qrA = qtA * 64 + w * 16 + l15;
  const int qrB = qtB * 64 + w * 16 + l15;
#pragma unroll
  for (int ks = 0; ks < 4; ++ks) {
    qfA[ks] = *reinterpret_cast<const f16x8*>(Qp + (size_t)qrA * N_HD + ks * 32 + g * 8);
    qfB[ks] = *reinterpret_cast<const f16x8*>(Qp + (size_t)qrB * N_HD + ks * 32 + g * 8);
  }

  f32x4 oA[8] = {}, oB[8] = {};
  float mA[4], lAr[4], mB[4], lBr[4];
#pragma unroll
  for (int r = 0; r < 4; ++r) {
    mA[r] = -3.0e38f; lAr[r] = 0.f;
    mB[r] = -3.0e38f; lBr[r] = 0.f;
  }
  const int q0A = qtA * 64 + w * 16 + 4 * g;
  const int q0B = qtB * 64 + w * 16 + 4 * g;

  const int nkt = qtB + 1;
  stage_kv(Kp, Vp, Klds[0], Vlds[0], 0, w, l);
  asm volatile("s_waitcnt vmcnt(0)" ::: "memory");
  __syncthreads();
  int cur = 0;
  for (int kt = 0; kt < nkt; ++kt) {
    if (kt + 1 < nkt)
      stage_kv(Kp, Vp, Klds[cur ^ 1], Vlds[cur ^ 1], kt + 1, w, l);
    attn_step(qfB, oB, mB, lBr, q0B, kt, Klds[cur], Vlds[cur], Plds[w], g, l15, kt == qtB);
    if (kt <= qtA)
      attn_step(qfA, oA, mA, lAr, q0A, kt, Klds[cur], Vlds[cur], Plds[w], g, l15, kt == qtA);
    asm volatile("s_waitcnt vmcnt(0)" ::: "memory");
    __syncthreads();
    cur ^= 1;
  }

  // normalize + write attn_out [B*S][NH*HD] fp16
#pragma unroll
  for (int r = 0; r < 4; ++r) {
    float invB = 1.0f / lBr[r];
    f16* orowB = O + (size_t)(b * NS + q0B + r) * NHID + h * N_HD;
#pragma unroll
    for (int dt = 0; dt < 8; ++dt) orowB[dt * 16 + l15] = (f16)(oB[dt][r] * invB);
    float invA = 1.0f / lAr[r];
    f16* orowA = O + (size_t)(b * NS + q0A + r) * NHID + h * N_HD;
#pragma unroll
    for (int dt = 0; dt < 8; ++dt) orowA[dt * 16 + l15] = (f16)(oA[dt][r] * invA);
  }
}

extern "C" void kernel_launch(void* const* d_in, const int* in_sizes, int n_in,
                              void* d_out, int out_size, void* d_ws, size_t ws_size,
                              hipStream_t stream) {
  const float* hs = (const float*)d_in[0];
  const float* Wq = (const float*)d_in[1];
  const float* Wk = (const float*)d_in[2];
  const float* Wv = (const float*)d_in[3];
  const float* Wo = (const float*)d_in[4];
  const float* bo = (const float*)d_in[5];
  float* out = (float*)d_out;

  char* ws = (char*)d_ws;
  // layout (bytes): X 16MB | Wqkv 12MB | Wo 8MB | Q 16MB | K 4MB | V 4MB | Vt 4MB  = 64MiB
  f16* Xh   = (f16*)(ws);
  f16* Wqkv = (f16*)(ws + 16777216);
  f16* Woh  = (f16*)(ws + 29360128);
  f16* Qb   = (f16*)(ws + 37748736);
  f16* Kb   = (f16*)(ws + 54525952);
  f16* Vb   = (f16*)(ws + 58720256);
  f16* Vtb  = (f16*)(ws + 62914560);
  f16* Ob   = Xh;  // X dead after QKV GEMM; reuse for attention output

  cvt_kernel<<<8192, 256, 0, stream>>>(hs, Xh, 2097152);
  cvt3_kernel<<<6144, 256, 0, stream>>>(Wq, 1048576, Wk, 262144, Wv, 262144, Wqkv);
  cvt_kernel<<<4096, 256, 0, stream>>>(Wo, Woh, 1048576);

  gemm_bt<0><<<dim3(24, 32), 256, 0, stream>>>(Xh, Wqkv, 2048, Qb, Kb, Vb, nullptr, nullptr);
  transpose_v<<<dim3(32, 2, 8), 256, 0, stream>>>(Vb, Vtb);
  attn_kernel<<<dim3(16, 32), 256, 0, stream>>>(Qb, Kb, Vtb, Ob);
  gemm_bt<1><<<dim3(16, 32), 256, 0, stream>>>(Ob, Woh, 2048, nullptr, nullptr, nullptr, out, bo);
}